// Round 1
// baseline (198.377 us; speedup 1.0000x reference)
//
#include <hip/hip_runtime.h>
#include <hip/hip_bf16.h>

// H=128, M=8, N=20000, E=320000
// Restructured math:
//   T[n]   = gelu(X[n] @ W_A^T) @ W_B^T                     (N x 8)
//   agg[d] = gelu( sum_{e:dst=d} outer(X[src_e], T[src_e]) ) (per-node 128x8, kept in regs)
//   S[d]   = sum_{e:dst=d} T[src_e]                          (N x 8)
//   out[d,h] = (1/max(cnt_d,1)) * sum_m agg[d,h,m] * S[d,m]
// Edges counting-sorted by dst so per-dst accumulation is atomic-free.

#define H 128
#define MDIM 8

__device__ __forceinline__ float gelu_f(float x) {
    // exact erf gelu (matches jax approximate=False)
    return 0.5f * x * (1.0f + erff(x * 0.7071067811865476f));
}

// ---------------- K0: zero the histogram ----------------
__global__ void k_zero(int* __restrict__ cnt, int N) {
    int i = blockIdx.x * 256 + threadIdx.x;
    if (i < N) cnt[i] = 0;
}

// ---------------- K1a: hid = gelu(X @ W_A^T), tiled fp32 GEMM ----------------
// grid: (ceil(N/64), 2), block 256. Block tile 64 nodes x 64 j; thread 4x4.
__global__ __launch_bounds__(256) void k_hidden(const float* __restrict__ X,
                                                const float* __restrict__ WA,
                                                float* __restrict__ hid, int N) {
    __shared__ float Xs[64][132];
    __shared__ float Ws[64][132];
    const int t  = threadIdx.x;
    const int n0 = blockIdx.x * 64;
    const int j0 = blockIdx.y * 64;

    // stage both tiles (64x128 each), coalesced float4
    #pragma unroll
    for (int i = 0; i < 8; ++i) {
        int idx = t + 256 * i;       // 0..2047
        int r   = idx >> 5;          // row 0..63
        int c4  = idx & 31;          // float4-col 0..31
        int gn  = n0 + r;
        float4 xv = make_float4(0.f, 0.f, 0.f, 0.f);
        if (gn < N) xv = *(const float4*)(X + (size_t)gn * H + c4 * 4);
        *(float4*)&Xs[r][c4 * 4] = xv;
        float4 wv = *(const float4*)(WA + (size_t)(j0 + r) * H + c4 * 4);
        *(float4*)&Ws[r][c4 * 4] = wv;
    }
    __syncthreads();

    const int tj = t & 15, tn = t >> 4;
    const int jb = tj * 4, nb = tn * 4;
    float acc[4][4] = {};

    for (int k = 0; k < H; k += 4) {
        float4 a[4], b[4];
        #pragma unroll
        for (int i = 0; i < 4; ++i) a[i] = *(const float4*)&Xs[nb + i][k];
        #pragma unroll
        for (int i = 0; i < 4; ++i) b[i] = *(const float4*)&Ws[jb + i][k];
        #pragma unroll
        for (int i = 0; i < 4; ++i)
            #pragma unroll
            for (int j = 0; j < 4; ++j)
                acc[i][j] += a[i].x * b[j].x + a[i].y * b[j].y +
                             a[i].z * b[j].z + a[i].w * b[j].w;
    }

    #pragma unroll
    for (int i = 0; i < 4; ++i) {
        int gn = n0 + nb + i;
        if (gn < N) {
            float4 o;
            o.x = gelu_f(acc[i][0]);
            o.y = gelu_f(acc[i][1]);
            o.z = gelu_f(acc[i][2]);
            o.w = gelu_f(acc[i][3]);
            *(float4*)(hid + (size_t)gn * H + j0 + jb) = o;
        }
    }
}

// ---------------- K1b: T = hid @ W_B^T ----------------
// grid ceil(N/32), block 256; thread -> (node, m)
__global__ __launch_bounds__(256) void k_mix(const float* __restrict__ hid,
                                             const float* __restrict__ WB,
                                             float* __restrict__ T, int N) {
    int t = threadIdx.x;
    int n = blockIdx.x * 32 + (t >> 3);
    int m = t & 7;
    if (n >= N) return;
    const float4* h4 = (const float4*)(hid + (size_t)n * H);
    const float4* w4 = (const float4*)(WB + (size_t)m * H);
    float acc = 0.f;
    #pragma unroll
    for (int q = 0; q < H / 4; ++q) {
        float4 h = h4[q], w = w4[q];
        acc += h.x * w.x + h.y * w.y + h.z * w.z + h.w * w.w;
    }
    T[n * MDIM + m] = acc;
}

// ---------------- K2: histogram of dst ----------------
__global__ void k_hist(const int* __restrict__ ei, int* __restrict__ cnt, int E) {
    int e = blockIdx.x * 256 + threadIdx.x;
    if (e < E) {
        int d = ei[E + e];   // dst row
        atomicAdd(&cnt[d], 1);
    }
}

// ---------------- K3a: per-256-chunk sums ----------------
__global__ void k_scan_a(const int* __restrict__ cnt, int* __restrict__ bsum, int N) {
    int idx = blockIdx.x * 256 + threadIdx.x;
    int v = (idx < N) ? cnt[idx] : 0;
    #pragma unroll
    for (int o = 32; o > 0; o >>= 1) v += __shfl_down(v, o, 64);
    __shared__ int s[4];
    if ((threadIdx.x & 63) == 0) s[threadIdx.x >> 6] = v;
    __syncthreads();
    if (threadIdx.x == 0) bsum[blockIdx.x] = s[0] + s[1] + s[2] + s[3];
}

// ---------------- K3b: scan chunk sums (C <= 128) ----------------
__global__ void k_scan_b(const int* __restrict__ bsum, int* __restrict__ bbase,
                         int* __restrict__ offs, int C, int Ntot, int Etot) {
    __shared__ int s[128];
    int t = threadIdx.x;
    int v = (t < C) ? bsum[t] : 0;
    s[t] = v;
    __syncthreads();
    for (int o = 1; o < 128; o <<= 1) {
        int x = (t >= o) ? s[t - o] : 0;
        __syncthreads();
        s[t] += x;
        __syncthreads();
    }
    if (t < C) bbase[t] = s[t] - v;   // exclusive
    if (t == 0) offs[Ntot] = Etot;
}

// ---------------- K3c: per-chunk exclusive scan -> offs; zero fill ----------------
__global__ void k_scan_c(const int* __restrict__ cnt, const int* __restrict__ bbase,
                         int* __restrict__ offs, int* __restrict__ fill, int N) {
    __shared__ int s[256];
    int t = threadIdx.x;
    int idx = blockIdx.x * 256 + t;
    int v = (idx < N) ? cnt[idx] : 0;
    s[t] = v;
    __syncthreads();
    for (int o = 1; o < 256; o <<= 1) {
        int x = (t >= o) ? s[t - o] : 0;
        __syncthreads();
        s[t] += x;
        __syncthreads();
    }
    if (idx < N) {
        offs[idx] = bbase[blockIdx.x] + s[t] - v;
        fill[idx] = 0;
    }
}

// ---------------- K4: scatter edges into dst-sorted order ----------------
__global__ void k_fill(const int* __restrict__ ei, const int* __restrict__ offs,
                       int* __restrict__ fill, int* __restrict__ sorted, int E) {
    int e = blockIdx.x * 256 + threadIdx.x;
    if (e < E) {
        int d = ei[E + e];
        int pos = offs[d] + atomicAdd(&fill[d], 1);
        sorted[pos] = ei[e];   // src
    }
}

// ---------------- K5: per-dst accumulate outer products, gelu, contract ----------------
// grid N, block 128 (thread = h). acc[m], S[m] in registers.
__global__ __launch_bounds__(128) void k_main(const float* __restrict__ X,
                                              const float* __restrict__ T,
                                              const int* __restrict__ offs,
                                              const int* __restrict__ sorted,
                                              float* __restrict__ out) {
    const int d = blockIdx.x;
    const int t = threadIdx.x;
    const int beg = offs[d];
    const int end = offs[d + 1];

    float acc[MDIM] = {};
    float S[MDIM] = {};

    for (int e = beg; e < end; ++e) {
        int s = sorted[e];
        float xv = X[(size_t)s * H + t];
        const float4* t4 = (const float4*)(T + (size_t)s * MDIM);
        float4 ta = t4[0], tb = t4[1];
        acc[0] += xv * ta.x;  S[0] += ta.x;
        acc[1] += xv * ta.y;  S[1] += ta.y;
        acc[2] += xv * ta.z;  S[2] += ta.z;
        acc[3] += xv * ta.w;  S[3] += ta.w;
        acc[4] += xv * tb.x;  S[4] += tb.x;
        acc[5] += xv * tb.y;  S[5] += tb.y;
        acc[6] += xv * tb.z;  S[6] += tb.z;
        acc[7] += xv * tb.w;  S[7] += tb.w;
    }

    int c = end - beg;
    float r = 0.f;
    if (c > 0) {
        #pragma unroll
        for (int m = 0; m < MDIM; ++m) r += gelu_f(acc[m]) * S[m];
        r /= (float)c;
    }
    out[(size_t)d * H + t] = r;
}

// ---------------- launch ----------------
extern "C" void kernel_launch(void* const* d_in, const int* in_sizes, int n_in,
                              void* d_out, int out_size, void* d_ws, size_t ws_size,
                              hipStream_t stream) {
    const float* X  = (const float*)d_in[0];
    const int*   ei = (const int*)d_in[1];
    const float* WA = (const float*)d_in[2];
    const float* WB = (const float*)d_in[3];
    float* out = (float*)d_out;

    const int N = in_sizes[0] / H;     // 20000
    const int E = in_sizes[1] / 2;     // 320000
    const int C = (N + 255) / 256;     // scan chunks (79)

    // workspace carve (all 16B-aligned blocks)
    char* w = (char*)d_ws;
    float* hid = (float*)w;  w += (size_t)N * H * sizeof(float);       // 10.24 MB
    float* T   = (float*)w;  w += (size_t)N * MDIM * sizeof(float);    // 0.64 MB
    int* cnt   = (int*)w;    w += (size_t)((N + 3) & ~3) * sizeof(int);
    int* offs  = (int*)w;    w += (size_t)((N + 4) & ~3) * sizeof(int);
    int* fill  = (int*)w;    w += (size_t)((N + 3) & ~3) * sizeof(int);
    int* bsum  = (int*)w;    w += 1024;
    int* bbase = (int*)w;    w += 1024;
    int* sorted = (int*)w;   // E ints

    k_zero<<<dim3((N + 255) / 256), dim3(256), 0, stream>>>(cnt, N);
    k_hidden<<<dim3((N + 63) / 64, 2), dim3(256), 0, stream>>>(X, WA, hid, N);
    k_mix<<<dim3((N + 31) / 32), dim3(256), 0, stream>>>(hid, WB, T, N);
    k_hist<<<dim3((E + 255) / 256), dim3(256), 0, stream>>>(ei, cnt, E);
    k_scan_a<<<dim3(C), dim3(256), 0, stream>>>(cnt, bsum, N);
    k_scan_b<<<dim3(1), dim3(128), 0, stream>>>(bsum, bbase, offs, C, N, E);
    k_scan_c<<<dim3(C), dim3(256), 0, stream>>>(cnt, bbase, offs, fill, N);
    k_fill<<<dim3((E + 255) / 256), dim3(256), 0, stream>>>(ei, offs, fill, sorted, E);
    k_main<<<dim3(N), dim3(128), 0, stream>>>(X, T, offs, sorted, out);
}